// Round 4
// baseline (220.913 us; speedup 1.0000x reference)
//
#include <hip/hip_runtime.h>
#include <hip/hip_bf16.h>
#include <stdint.h>

#define T_TOK 131072
#define DIM   512
#define NBR   8
#define BM    64
#define BK    32
#define NKT   (DIM / BK)   // 16
#define GT    512          // gemm threads (8 waves)
#define MT    288          // max row-tiles per branch

typedef __attribute__((ext_vector_type(8))) __bf16 bf16x8;
typedef __attribute__((ext_vector_type(4))) float  f32x4;
typedef unsigned short ushort_t;

__device__ __forceinline__ unsigned short f2bf(float f) {
  union { float f; unsigned int u; } v; v.f = f;
  unsigned int r = v.u + 0x7fffu + ((v.u >> 16) & 1u);
  return (unsigned short)(r >> 16);
}

// ---------------- prep kernels ----------------

__global__ void k_init(int* counts) {
  if (threadIdx.x < NBR) counts[threadIdx.x] = 0;
}

__global__ __launch_bounds__(512) void k_bhist(const int* __restrict__ bidx,
                                               int* __restrict__ counts) {
  __shared__ int h[NBR];
  if (threadIdx.x < NBR) h[threadIdx.x] = 0;
  __syncthreads();
  int t = blockIdx.x * 512 + threadIdx.x;
  atomicAdd(&h[bidx[t]], 1);
  __syncthreads();
  if (threadIdx.x < NBR) atomicAdd(&counts[threadIdx.x], h[threadIdx.x]);
}

__global__ void k_off(const int* __restrict__ counts, int* __restrict__ offsets,
                      int* __restrict__ cursors) {
  if (threadIdx.x == 0) {
    int s = 0;
    for (int n = 0; n < NBR; ++n) { offsets[n] = s; cursors[n] = s; s += counts[n]; }
  }
}

__global__ __launch_bounds__(512) void k_scatter(const int* __restrict__ bidx,
                                                 int* __restrict__ cursors,
                                                 int* __restrict__ perm) {
  __shared__ int h[NBR], base[NBR];
  if (threadIdx.x < NBR) h[threadIdx.x] = 0;
  __syncthreads();
  int t = blockIdx.x * 512 + threadIdx.x;
  int b = bidx[t];
  int rank = atomicAdd(&h[b], 1);
  __syncthreads();
  if (threadIdx.x < NBR)
    base[threadIdx.x] = atomicAdd(&cursors[threadIdx.x], h[threadIdx.x]);
  __syncthreads();
  perm[base[b] + rank] = t;
}

// W (N,D,D) fp32 row-major -> Wt bf16 tiled [b][kt][c][kk], kk = k % 32
__global__ __launch_bounds__(256) void k_wtrans(const float* __restrict__ W,
                                                ushort_t* __restrict__ Wt) {
  __shared__ float tile[BK][129];
  int blk = blockIdx.x;          // 8 * 16 * 4 = 512 blocks
  int b  = blk >> 6;
  int kt = (blk >> 2) & 15;
  int cb = blk & 3;
  int t = threadIdx.x;
  #pragma unroll
  for (int i = 0; i < 4; ++i) {
    int idx4 = i * 256 + t;
    int kr = idx4 >> 5;
    int c4 = idx4 & 31;
    const float* src = W + (((size_t)b * DIM + (size_t)(kt * BK + kr)) * DIM + cb * 128 + c4 * 4);
    float4 v = *(const float4*)src;
    tile[kr][c4 * 4 + 0] = v.x;
    tile[kr][c4 * 4 + 1] = v.y;
    tile[kr][c4 * 4 + 2] = v.z;
    tile[kr][c4 * 4 + 3] = v.w;
  }
  __syncthreads();
  int c  = t >> 1;
  int kh = t & 1;
  unsigned int p[8];
  #pragma unroll
  for (int i = 0; i < 8; ++i) {
    unsigned short lo = f2bf(tile[kh * 16 + i * 2 + 0][c]);
    unsigned short hi = f2bf(tile[kh * 16 + i * 2 + 1][c]);
    p[i] = (unsigned int)lo | ((unsigned int)hi << 16);
  }
  size_t obase = (((size_t)b * 16 + kt) * DIM + (size_t)(cb * 128 + c)) * BK + kh * 16;
  uint4 q0; q0.x = p[0]; q0.y = p[1]; q0.z = p[2]; q0.w = p[3];
  uint4 q1; q1.x = p[4]; q1.y = p[5]; q1.z = p[6]; q1.w = p[7];
  *(uint4*)&Wt[obase]     = q0;
  *(uint4*)&Wt[obase + 8] = q1;
}

// ---------------- grouped GEMM ----------------
// Block: 64 rows x 512 cols, 8 waves (wave 64x64), 16x16x32 MFMA.
// R4 theme: ALL HBM access at 1-2KB contiguous granules (DRAM page locality).
//  Phase 1: wave w stages rows w*8..w*8+7; each wave-load = 1KB of ONE row.
//           LDS dest = frag-linear with kt&7 slot-XOR (reads conflict-free).
//  Phase 2: barrier-free k-loop; B frags from L2/L3-resident Wt, depth-1.
//  Epilogue: transpose via LDS (reuse As, 2 passes x 32 rows); each wave
//           stores whole 2KB rows as 2 x 1KB dwordx4.
__global__ __launch_bounds__(GT, 4)
void k_gemm(const float* __restrict__ x, const float* __restrict__ bias,
            const ushort_t* __restrict__ Wt,
            const int* __restrict__ counts, const int* __restrict__ offsets,
            const int* __restrict__ perm, float* __restrict__ out) {
  __shared__ __align__(16) ushort_t As[NKT * 4 * 64 * 8];   // 64 KB
  __shared__ int rowIdx[BM];
  float* Ot = (float*)As;                                   // epilogue reuse: [32][512] f32

  const int tid = threadIdx.x;
  const int l = tid & 63;
  const int w = tid >> 6;

  const int b  = blockIdx.x / MT;     // branch-major
  const int lt = blockIdx.x % MT;
  const int cnt = counts[b];
  const int row0 = lt * BM;
  if (row0 >= cnt) return;
  const int gstart = offsets[b];
  const int vrows = min(BM, cnt - row0);

  if (tid < BM) {
    int r = row0 + tid; if (r >= cnt) r = cnt - 1;
    rowIdx[tid] = perm[gstart + r];
  }
  __syncthreads();

  // ---- Phase 1: stage A, 1KB-contiguous loads, 16-deep MLP ----
  {
    float4 v[8][2];
    #pragma unroll
    for (int j = 0; j < 8; ++j) {
      const float* rp = x + (size_t)rowIdx[w * 8 + j] * DIM;
      #pragma unroll
      for (int i = 0; i < 2; ++i)
        v[j][i] = *(const float4*)(rp + i * 256 + l * 4);
    }
    // data (row r = w*8+j, k = i*256 + l*4 .. +3) -> frag-linear slot
    const int rf  = w >> 1;
    const int Llo = (w & 1) * 8;        // + j
    const int Lhi = (l & 7) >> 1;
    const int e0  = (l & 1) * 4;
    const int ktl = l >> 3;             // kt low 3 bits = XOR key
    #pragma unroll
    for (int j = 0; j < 8; ++j) {
      #pragma unroll
      for (int i = 0; i < 2; ++i) {
        int f = (i * 8 + ktl) * 4 + rf;
        int slot = (Lhi * 16 + Llo + j) ^ ktl;
        ushort4 a4;
        a4.x = f2bf(v[j][i].x); a4.y = f2bf(v[j][i].y);
        a4.z = f2bf(v[j][i].z); a4.w = f2bf(v[j][i].w);
        *(ushort4*)&As[f * 512 + slot * 8 + e0] = a4;
      }
    }
  }
  __syncthreads();

  // ---- Phase 2: barrier-free compute ----
  const ushort_t* wtile = Wt + (size_t)b * (NKT * BK * DIM);
  int bBase[4];
  #pragma unroll
  for (int cf = 0; cf < 4; ++cf)
    bBase[cf] = (w * 64 + cf * 16 + (l & 15)) * BK + (l >> 4) * 8;

  f32x4 acc[4][4];
  #pragma unroll
  for (int rf = 0; rf < 4; ++rf)
    #pragma unroll
    for (int cf = 0; cf < 4; ++cf) acc[rf][cf] = (f32x4){0.f, 0.f, 0.f, 0.f};

  bf16x8 bq[4];
  #pragma unroll
  for (int cf = 0; cf < 4; ++cf) bq[cf] = *(const bf16x8*)(wtile + bBase[cf]);

  #pragma unroll
  for (int kt = 0; kt < NKT; ++kt) {
    bf16x8 bqn[4];
    if (kt + 1 < NKT) {
      const ushort_t* wtk = wtile + (kt + 1) * (BK * DIM);
      #pragma unroll
      for (int cf = 0; cf < 4; ++cf) bqn[cf] = *(const bf16x8*)(wtk + bBase[cf]);
    }
    const int lsw = (l ^ (kt & 7)) * 8;
    bf16x8 af[4];
    #pragma unroll
    for (int rf = 0; rf < 4; ++rf)
      af[rf] = *(const bf16x8*)&As[(kt * 4 + rf) * 512 + lsw];
    #pragma unroll
    for (int cf = 0; cf < 4; ++cf)
      #pragma unroll
      for (int rf = 0; rf < 4; ++rf)
        acc[rf][cf] = __builtin_amdgcn_mfma_f32_16x16x32_bf16(af[rf], bq[cf], acc[rf][cf], 0, 0, 0);
    if (kt + 1 < NKT) {
      #pragma unroll
      for (int cf = 0; cf < 4; ++cf) bq[cf] = bqn[cf];
    }
  }

  // ---- Epilogue: LDS transpose -> whole-row 1KB stores ----
  float bv[4];
  #pragma unroll
  for (int cf = 0; cf < 4; ++cf) bv[cf] = bias[b * DIM + w * 64 + cf * 16 + (l & 15)];

  __syncthreads();   // As no longer needed as A; reuse as Ot
  #pragma unroll
  for (int p = 0; p < 2; ++p) {
    // stage rows p*32..p*32+31 (rf = 2p, 2p+1), XOR-swizzled (2-way-free)
    #pragma unroll
    for (int rr = 0; rr < 2; ++rr) {
      int rf = p * 2 + rr;
      #pragma unroll
      for (int j = 0; j < 4; ++j) {
        int rip = rr * 16 + (l >> 4) * 4 + j;   // row within pass
        int sxk = (rip & 7) << 2;               // float-index XOR key
        #pragma unroll
        for (int cf = 0; cf < 4; ++cf) {
          int col = w * 64 + cf * 16 + (l & 15);
          Ot[rip * 512 + (col ^ sxk)] = acc[rf][cf][j] + bv[cf];
        }
      }
    }
    __syncthreads();
    // each wave drains 4 whole rows: 2 x 1KB contiguous stores per row
    #pragma unroll
    for (int q = 0; q < 4; ++q) {
      int rip = w * 4 + q;
      int grow = p * 32 + rip;
      if (grow < vrows) {
        float* op = out + (size_t)rowIdx[grow] * DIM;
        int s = rip & 7;
        #pragma unroll
        for (int h = 0; h < 2; ++h) {
          float4 vv = *(const float4*)&Ot[rip * 512 + h * 256 + l * 4];
          *(float4*)(op + h * 256 + ((l ^ s) * 4)) = vv;
        }
      }
    }
    if (p == 0) __syncthreads();
  }
}

// ---------------- launcher ----------------
// ws layout: [0,32) counts | [64,96) cursors | [128,160) offsets |
//            [256, 256+4T) perm | [1MB, 1MB+4MB) Wt bf16
extern "C" void kernel_launch(void* const* d_in, const int* in_sizes, int n_in,
                              void* d_out, int out_size, void* d_ws, size_t ws_size,
                              hipStream_t stream) {
  const float* x    = (const float*)d_in[0];
  const int*   bidx = (const int*)d_in[1];
  const float* W    = (const float*)d_in[2];
  const float* bias = (const float*)d_in[3];
  float* out = (float*)d_out;

  char* ws = (char*)d_ws;
  int* counts  = (int*)(ws + 0);
  int* cursors = (int*)(ws + 64);
  int* offsets = (int*)(ws + 128);
  int* perm    = (int*)(ws + 256);
  ushort_t* Wt = (ushort_t*)(ws + (1u << 20));

  k_init<<<1, 64, 0, stream>>>(counts);
  k_bhist<<<T_TOK / 512, 512, 0, stream>>>(bidx, counts);
  k_off<<<1, 64, 0, stream>>>(counts, offsets, cursors);
  k_scatter<<<T_TOK / 512, 512, 0, stream>>>(bidx, cursors, perm);
  k_wtrans<<<512, 256, 0, stream>>>(W, Wt);
  k_gemm<<<NBR * MT, GT, 0, stream>>>(x, bias, Wt, counts, offsets, perm, out);
}